// Round 3
// baseline (866.595 us; speedup 1.0000x reference)
//
#include <hip/hip_runtime.h>

// Problem constants (match reference: B=16, S=4096, D=128)
#define BB   16
#define SS   4096
#define DD   128
#define NCH  512                 // chunks per batch
#define TT   (SS / NCH)          // 8 steps per chunk
#define WPB  4                   // waves (=chunks) per block
#define NTHR 256
#define NWAVE (BB * NCH)         // 8192 chunks total
#define NBLK  (NWAVE / WPB)      // 2048 blocks

#define LN_EPS  1e-5f
#define REC_EPS 1e-8f
#define AGENT   __HIP_MEMORY_SCOPE_AGENT

__device__ __forceinline__ float fast_rcp(float x) { return __builtin_amdgcn_rcpf(x); }
__device__ __forceinline__ float sigm(float x) { return fast_rcp(1.0f + __expf(-x)); }

// DPP shifted copy with 0-fill (bound_ctrl=1). CTRL is a compile-time const.
template<int CTRL>
__device__ __forceinline__ float dpp_mov0(float x) {
    return __int_as_float(
        __builtin_amdgcn_update_dpp(0, __float_as_int(x), CTRL, 0xF, 0xF, true));
}

// Full 64-lane wave sum of two values, VALU-only (HW-verified in prior rounds).
__device__ __forceinline__ void wave_red2(float& a, float& b) {
    a += dpp_mov0<0x111>(a); b += dpp_mov0<0x111>(b);   // row_shr:1
    a += dpp_mov0<0x112>(a); b += dpp_mov0<0x112>(b);   // row_shr:2
    a += dpp_mov0<0x114>(a); b += dpp_mov0<0x114>(b);   // row_shr:4
    a += dpp_mov0<0x118>(a); b += dpp_mov0<0x118>(b);   // row_shr:8
    a += dpp_mov0<0x142>(a); b += dpp_mov0<0x142>(b);   // row_bcast:15
    a += dpp_mov0<0x143>(a); b += dpp_mov0<0x143>(b);   // row_bcast:31
    a = __int_as_float(__builtin_amdgcn_readlane(__float_as_int(a), 63));
    b = __int_as_float(__builtin_amdgcn_readlane(__float_as_int(b), 63));
}

#define LOAD_FENCE() asm volatile("" ::: "memory")

// relaxed agent-scope atomics: payload goes to/comes from the coherence point,
// sidestepping per-XCD L2 non-coherence.
__device__ __forceinline__ float aload(float* p) {
    return __hip_atomic_load(p, __ATOMIC_RELAXED, AGENT);
}
__device__ __forceinline__ void astore(float* p, float v) {
    __hip_atomic_store(p, v, __ATOMIC_RELAXED, AGENT);
}

// ---------------------------------------------------------------------------
// Single-pass decoupled-lookback scan + fused LayerNorm.
// One wave per chunk; chunk order == dispatch order (gc = blockIdx*WPB + wv,
// ch = gc>>4 so lower chunk ids live in lower blockIdx -> in-order dispatch
// guarantees predecessors run; spin uses s_sleep).
// flags[gc]: 0 = nothing, 1 = aggregate published, 2 = inclusive prefix
// published. Payload stores are relaxed agent atomics; flag store is release,
// flag probe is acquire.
// ---------------------------------------------------------------------------
__global__ __launch_bounds__(NTHR, 4) void fused_kernel(
    const float* __restrict__ C, const float* __restrict__ V, const float* __restrict__ W,
    const float* __restrict__ enc, const float* __restrict__ tmod, const float* __restrict__ cmod,
    const float* __restrict__ lnw, const float* __restrict__ lnb,
    float* __restrict__ aggP, float* __restrict__ aggQ, float* __restrict__ incB,
    float* __restrict__ aggPa, float* __restrict__ aggQa, float* __restrict__ incA,
    int* __restrict__ flags,
    float* __restrict__ out)
{
    const int wv   = threadIdx.x >> 6;
    const int lane = threadIdx.x & 63;
    const int gc   = blockIdx.x * WPB + wv;   // chunk id in dispatch order
    const int b    = gc & (BB - 1);           // batch (minor)
    const int ch   = gc >> 4;                 // chunk within batch (major)
    const int d2   = lane << 1;

    const int t0 = ch * TT;
    const size_t base = ((size_t)b * SS + t0) * DD + d2;
    const float2* Cp = (const float2*)(C + base);
    const float2* Vp = (const float2*)(V + base);
    const float2* Wp = (const float2*)(W + base);

    const float2 tm = *(const float2*)(tmod + d2);
    const float2 cm = *(const float2*)(cmod + d2);
    const float2 ec = *(const float2*)(enc + b * DD + d2);

    // ---- phase A: load chunk, build dec/T (fp32, stays in VGPRs) ----
    float2 cR[TT], wR[TT], vR[TT];
#pragma unroll
    for (int t = 0; t < TT; ++t) {
        cR[t] = Cp[t * (DD / 2)];
        wR[t] = Wp[t * (DD / 2)];
        vR[t] = Vp[t * (DD / 2)];
    }
    LOAD_FENCE();

    float2 ctx;
    ctx.x = sigm(ec.x * cm.x) * ec.x;
    ctx.y = sigm(ec.y * cm.y) * ec.y;

    float2 decR[TT], TR[TT];
    float2 P = make_float2(1.f, 1.f);
    float2 Q = make_float2(0.f, 0.f);
    float sdp[TT], sep[TT];

#pragma unroll
    for (int t = 0; t < TT; ++t) {
        float2 dec, e2, T2;
        dec.x = sigm(wR[t].x * tm.x); dec.y = sigm(wR[t].y * tm.y);
        e2.x = __expf(cR[t].x); e2.y = __expf(cR[t].y);
        T2.x = e2.x * vR[t].x + ctx.x;
        T2.y = e2.y * vR[t].y + ctx.y;
        decR[t] = dec; TR[t] = T2;

        Q.x = dec.x * Q.x + T2.x;
        Q.y = dec.y * Q.y + T2.y;
        P.x *= dec.x; P.y *= dec.y;

        sdp[t] = dec.x + dec.y;
        sep[t] = e2.x + e2.y;
    }

    // batched wave reductions (TT independent trees, full ILP)
#pragma unroll
    for (int t = 0; t < TT; ++t) wave_red2(sdp[t], sep[t]);

    float pa = 1.f, qa = 0.f, mk = 0.f, ek = 0.f;
#pragma unroll
    for (int t = 0; t < TT; ++t) {
        const float mt = sdp[t] * (1.0f / DD);
        pa *= mt;
        qa = mt * qa + sep[t];
        if (lane == t) { mk = mt; ek = sep[t]; }
    }

    // ---- publish aggregate (so successors never wait on our lookback) ----
    const size_t pb = (size_t)gc * DD + d2;
    if (ch > 0) {
        astore(aggP + pb,     P.x); astore(aggP + pb + 1, P.y);
        astore(aggQ + pb,     Q.x); astore(aggQ + pb + 1, Q.y);
        if (lane == 0) {
            astore(aggPa + gc, pa); astore(aggQa + gc, qa);
            __hip_atomic_store(flags + gc, 1, __ATOMIC_RELEASE, AGENT);
        }
    }

    // ---- lookback: resolve entry state ----
    float2 entry; float entryA;
    if (ch == 0) {
        entry = make_float2(0.f, 0.f); entryA = 0.f;
    } else {
        float2 FP = make_float2(1.f, 1.f), FQ = make_float2(0.f, 0.f);
        float fpa = 1.f, fqa = 0.f;
        int j = ch - 1;
        bool done = false;
        while (!done) {
            // probe up to 8 predecessor flags at once (lanes 0..7)
            const int pj = j - (int)lane;
            int fl = 0;
            if (lane < 8 && pj >= 0)
                fl = __hip_atomic_load(flags + pj * BB + b, __ATOMIC_ACQUIRE, AGENT);
            const unsigned long long mr = __ballot(fl >= 1);
            const unsigned long long mp = __ballot(fl == 2);
            int r = (int)__ffsll(~mr) - 1;          // contiguous ready run from j
            if (r <= 0) { __builtin_amdgcn_s_sleep(4); continue; }
            if (r > 8) r = 8;
            const int pp = (int)__ffsll(mp) - 1;    // nearest prefix (-1 if none)
            const bool hasP = (pp >= 0 && pp < r);
            const int steps = hasP ? pp : r;        // # aggregates to compose

            if (steps > 0) {
                float2 Pp[8], Qp[8]; float ppa[8], qpa[8];
#pragma unroll
                for (int i = 0; i < 8; ++i) {
                    int idx = j - i; if (idx < 0) idx = 0;
                    const size_t bi = ((size_t)idx * BB + b) * DD + d2;
                    Pp[i].x = aload(aggP + bi); Pp[i].y = aload(aggP + bi + 1);
                    Qp[i].x = aload(aggQ + bi); Qp[i].y = aload(aggQ + bi + 1);
                    ppa[i] = aload(aggPa + idx * BB + b);
                    qpa[i] = aload(aggQa + idx * BB + b);
                }
#pragma unroll
                for (int i = 0; i < 8; ++i) {
                    if (i < steps) {
                        FQ.x = FP.x * Qp[i].x + FQ.x; FQ.y = FP.y * Qp[i].y + FQ.y;
                        FP.x *= Pp[i].x;              FP.y *= Pp[i].y;
                        fqa = fpa * qpa[i] + fqa;     fpa *= ppa[i];
                    }
                }
            }
            if (hasP) {
                const int idx = j - pp;
                const size_t bi = ((size_t)idx * BB + b) * DD + d2;
                const float bx = aload(incB + bi), by = aload(incB + bi + 1);
                const float ia = aload(incA + idx * BB + b);
                entry.x = FP.x * bx + FQ.x;
                entry.y = FP.y * by + FQ.y;
                entryA  = fpa * ia + fqa;
                done = true;
            } else {
                j -= r;
                if (j < 0) { entry = FQ; entryA = fqa; done = true; }
            }
        }
    }

    // ---- publish inclusive prefix (flag=2) ----
    {
        const float ix = P.x * entry.x + Q.x;
        const float iy = P.y * entry.y + Q.y;
        astore(incB + pb,     ix); astore(incB + pb + 1, iy);
        if (lane == 0) {
            astore(incA + gc, pa * entryA + qa);
            __hip_atomic_store(flags + gc, 2, __ATOMIC_RELEASE, AGENT);
        }
    }

    // ---- phase C: replay from registers + fused LayerNorm ----
    const float2 gw = *(const float2*)(lnw + d2);
    const float2 gb = *(const float2*)(lnb + d2);
    float2* Op = (float2*)(out + base);

    float a = entryA;
    float2 bst = entry;
    float2 o[TT]; float s1p[TT], s2p[TT];
#pragma unroll
    for (int t = 0; t < TT; ++t) {
        const float mt = __int_as_float(__builtin_amdgcn_readlane(__float_as_int(mk), t));
        const float et = __int_as_float(__builtin_amdgcn_readlane(__float_as_int(ek), t));
        a = mt * a + et;
        bst.x = decR[t].x * bst.x + TR[t].x;
        bst.y = decR[t].y * bst.y + TR[t].y;
        const float inva = fast_rcp(a + REC_EPS);
        o[t].x = bst.x * inva; o[t].y = bst.y * inva;
        s1p[t] = o[t].x + o[t].y;
        s2p[t] = o[t].x * o[t].x + o[t].y * o[t].y;
    }

#pragma unroll
    for (int t = 0; t < TT; ++t) wave_red2(s1p[t], s2p[t]);

#pragma unroll
    for (int t = 0; t < TT; ++t) {
        const float mu  = s1p[t] * (1.0f / DD);
        const float var = s2p[t] * (1.0f / DD) - mu * mu;
        const float rs  = rsqrtf(var + LN_EPS);
        float2 r;
        r.x = (o[t].x - mu) * rs * gw.x + gb.x;
        r.y = (o[t].y - mu) * rs * gw.y + gb.y;
        Op[t * (DD / 2)] = r;
    }
}

extern "C" void kernel_launch(void* const* d_in, const int* in_sizes, int n_in,
                              void* d_out, int out_size, void* d_ws, size_t ws_size,
                              hipStream_t stream)
{
    const float* C    = (const float*)d_in[0];
    const float* V    = (const float*)d_in[1];
    const float* W    = (const float*)d_in[2];
    const float* enc  = (const float*)d_in[3];
    const float* tmod = (const float*)d_in[4];
    const float* cmod = (const float*)d_in[5];
    const float* lnw  = (const float*)d_in[6];
    const float* lnb  = (const float*)d_in[7];
    float* out = (float*)d_out;

    // Workspace: lookback state (~12.1 MB)
    float* ws    = (float*)d_ws;
    float* aggP  = ws;                                  // NWAVE*DD
    float* aggQ  = aggP  + (size_t)NWAVE * DD;
    float* incB  = aggQ  + (size_t)NWAVE * DD;
    float* aggPa = incB  + (size_t)NWAVE * DD;          // NWAVE
    float* aggQa = aggPa + NWAVE;
    float* incA  = aggQa + NWAVE;
    int*   flags = (int*)(incA + NWAVE);                // NWAVE ints

    hipMemsetAsync(flags, 0, NWAVE * sizeof(int), stream);
    fused_kernel<<<NBLK, NTHR, 0, stream>>>(C, V, W, enc, tmod, cmod, lnw, lnb,
                                            aggP, aggQ, incB, aggPa, aggQa, incA,
                                            flags, out);
}

// Round 6
// 163.655 us; speedup vs baseline: 5.2953x; 5.2953x over previous
//
#include <hip/hip_runtime.h>

// Problem constants (match reference: B=16, S=4096, D=128)
#define BB   16
#define SS   4096
#define DD   128
#define NCH  512                 // chunks per batch
#define TT   (SS / NCH)          // 8 steps per chunk
#define WPB  4                   // waves per block
#define NTHR 256
#define NWAVE (BB * NCH)         // 8192 chunks total
#define KCH  4                   // chunks per wave (software pipeline)
#define NW1  (NWAVE / KCH)       // 2048 persistent waves
#define NBLK1 (NW1 / WPB)        // 512 blocks (2 per CU, all resident)

// pass2 two-level scan geometry
#define DTILE 16                 // d's per pass2 block
#define SUBS  16                 // sub-ranges per (b,d)
#define CPS   (NCH / SUBS)       // 32 chunks per sub-range

#define LN_EPS  1e-5f
#define REC_EPS 1e-8f

__device__ __forceinline__ float fast_rcp(float x) { return __builtin_amdgcn_rcpf(x); }
__device__ __forceinline__ float sigm(float x) { return fast_rcp(1.0f + __expf(-x)); }

// pack two floats as bf16 pair: lo16 = a, hi16 = b (round-half-up in magnitude)
__device__ __forceinline__ unsigned pack2(float a, float b) {
    unsigned ua = (__float_as_uint(a) + 0x8000u) >> 16;
    unsigned ub = (__float_as_uint(b) + 0x8000u) & 0xFFFF0000u;
    return ub | ua;
}
__device__ __forceinline__ float up_lo(unsigned u) { return __uint_as_float(u << 16); }
__device__ __forceinline__ float up_hi(unsigned u) { return __uint_as_float(u & 0xFFFF0000u); }

// DPP shifted copy with 0-fill (bound_ctrl=1). CTRL is a compile-time const.
template<int CTRL>
__device__ __forceinline__ float dpp_mov0(float x) {
    return __int_as_float(
        __builtin_amdgcn_update_dpp(0, __float_as_int(x), CTRL, 0xF, 0xF, true));
}

// Full 64-lane wave sum of two values, VALU-only (HW-verified in prior rounds).
__device__ __forceinline__ void wave_red2(float& a, float& b) {
    a += dpp_mov0<0x111>(a); b += dpp_mov0<0x111>(b);   // row_shr:1
    a += dpp_mov0<0x112>(a); b += dpp_mov0<0x112>(b);   // row_shr:2
    a += dpp_mov0<0x114>(a); b += dpp_mov0<0x114>(b);   // row_shr:4
    a += dpp_mov0<0x118>(a); b += dpp_mov0<0x118>(b);   // row_shr:8
    a += dpp_mov0<0x142>(a); b += dpp_mov0<0x142>(b);   // row_bcast:15
    a += dpp_mov0<0x143>(a); b += dpp_mov0<0x143>(b);   // row_bcast:31
    a = __int_as_float(__builtin_amdgcn_readlane(__float_as_int(a), 63));
    b = __int_as_float(__builtin_amdgcn_readlane(__float_as_int(b), 63));
}

// ---------------------------------------------------------------------------
// Pass 1 (pipelined): each wave streams KCH=4 consecutive chunks; loads of
// chunk k+1 fly under compute of chunk k (register double-buffer, no
// barriers -> compiler emits fine-grained vmcnt, no drain points).
// Numerics per chunk are bit-identical to the R2-passing kernel.
// ---------------------------------------------------------------------------
__global__ __launch_bounds__(NTHR, 2) void pass1_kernel(
    const float* __restrict__ C, const float* __restrict__ V, const float* __restrict__ W,
    const float* __restrict__ enc, const float* __restrict__ tmod, const float* __restrict__ cmod,
    unsigned* __restrict__ DTb,
    float* __restrict__ Pbuf, float* __restrict__ Qbuf,
    float* __restrict__ PaBuf, float* __restrict__ QaBuf,
    float2* __restrict__ MEbuf)
{
    const int wv   = threadIdx.x >> 6;
    const int lane = threadIdx.x & 63;
    const int wid  = blockIdx.x * WPB + wv;    // 0..2047
    const int gc0  = wid * KCH;                // first chunk (4 consecutive, same b)
    const int b    = gc0 >> 9;                 // / NCH
    const int ch0  = gc0 & (NCH - 1);
    const int d2   = lane << 1;

    const size_t base = ((size_t)b * SS + ch0 * TT) * DD + d2;
    const float2* Cp = (const float2*)(C + base);
    const float2* Vp = (const float2*)(V + base);
    const float2* Wp = (const float2*)(W + base);
    uint2* DTp = (uint2*)(DTb + base);

    const float2 tm = *(const float2*)(tmod + d2);
    const float2 cm = *(const float2*)(cmod + d2);
    const float2 ec = *(const float2*)(enc + b * DD + d2);
    float2 ctx;
    ctx.x = sigm(ec.x * cm.x) * ec.x;
    ctx.y = sigm(ec.y * cm.y) * ec.y;

    float2 cA[TT], wA[TT], vA[TT], cB[TT], wB[TT], vB[TT];

#define LD1(X, k) do { \
    const int off_ = (k) * (TT * DD / 2); \
    _Pragma("unroll") \
    for (int t = 0; t < TT; ++t) { \
        c##X[t] = Cp[off_ + t * (DD / 2)]; \
        w##X[t] = Wp[off_ + t * (DD / 2)]; \
        v##X[t] = Vp[off_ + t * (DD / 2)]; \
    } \
} while (0)

#define CH1(X, k) do { \
    float2 P = make_float2(1.f, 1.f), Q = make_float2(0.f, 0.f); \
    float sdp[TT], sep[TT]; \
    const int off_ = (k) * (TT * DD / 2); \
    _Pragma("unroll") \
    for (int t = 0; t < TT; ++t) { \
        float2 dec, e2, T2; uint2 u; \
        dec.x = sigm(w##X[t].x * tm.x); dec.y = sigm(w##X[t].y * tm.y); \
        e2.x = __expf(c##X[t].x); e2.y = __expf(c##X[t].y); \
        T2.x = e2.x * v##X[t].x + ctx.x; \
        T2.y = e2.y * v##X[t].y + ctx.y; \
        u.x = pack2(dec.x, T2.x); u.y = pack2(dec.y, T2.y); \
        DTp[off_ + t * (DD / 2)] = u; \
        const float dqx = up_lo(u.x), dqy = up_lo(u.y); \
        const float tqx = up_hi(u.x), tqy = up_hi(u.y); \
        Q.x = dqx * Q.x + tqx; Q.y = dqy * Q.y + tqy; \
        P.x *= dqx; P.y *= dqy; \
        sdp[t] = dec.x + dec.y; sep[t] = e2.x + e2.y; \
    } \
    _Pragma("unroll") \
    for (int t = 0; t < TT; ++t) wave_red2(sdp[t], sep[t]); \
    float pa = 1.f, qa = 0.f, mk = 0.f, ek = 0.f; \
    _Pragma("unroll") \
    for (int t = 0; t < TT; ++t) { \
        const float mt = sdp[t] * (1.0f / DD); \
        pa *= mt; qa = mt * qa + sep[t]; \
        if (lane == t) { mk = mt; ek = sep[t]; } \
    } \
    const int gc_ = gc0 + (k); \
    *(float2*)(Pbuf + (size_t)gc_ * DD + d2) = P; \
    *(float2*)(Qbuf + (size_t)gc_ * DD + d2) = Q; \
    if (lane < TT) MEbuf[(size_t)b * SS + (ch0 + (k)) * TT + lane] = make_float2(mk, ek); \
    if (lane == 0) { PaBuf[gc_] = pa; QaBuf[gc_] = qa; } \
} while (0)

    LD1(A, 0);
    LD1(B, 1);
    CH1(A, 0);
    LD1(A, 2);
    CH1(B, 1);
    LD1(B, 3);
    CH1(A, 2);
    CH1(B, 3);

#undef LD1
#undef CH1
}

// ---------------------------------------------------------------------------
// Pass 2: two-level scan of chunk transfer functions -> chunk-entry states.
// (unchanged from the passing R2 kernel)
// ---------------------------------------------------------------------------
__global__ __launch_bounds__(256, 2) void pass2_kernel(
    const float* __restrict__ Pbuf, const float* __restrict__ Qbuf,
    const float* __restrict__ PaBuf, const float* __restrict__ QaBuf,
    float* __restrict__ bst0, float* __restrict__ a0)
{
    const int b   = blockIdx.x >> 3;
    const int dt  = blockIdx.x & 7;
    const int tid = threadIdx.x;
    const int dl  = tid & (DTILE - 1);
    const int sub = tid >> 4;
    const int d   = dt * DTILE + dl;

    __shared__ float cP[SUBS][DTILE], cQ[SUBS][DTILE], ent[SUBS][DTILE];
    __shared__ float sPa[256], sQa[256];

    const int ch0 = sub * CPS;
    const size_t base = ((size_t)b * NCH + ch0) * DD + d;
    float Pr[CPS], Qr[CPS];
    float p = 1.f, q = 0.f;
#pragma unroll
    for (int i = 0; i < CPS; ++i) {
        Pr[i] = Pbuf[base + (size_t)i * DD];
        Qr[i] = Qbuf[base + (size_t)i * DD];
        q = Pr[i] * q + Qr[i];
        p = Pr[i] * p;
    }
    cP[sub][dl] = p; cQ[sub][dl] = q;
    __syncthreads();

    if (tid < DTILE) {
        float s = 0.f;
#pragma unroll
        for (int sb = 0; sb < SUBS; ++sb) {
            ent[sb][tid] = s;
            s = cP[sb][tid] * s + cQ[sb][tid];
        }
    }
    __syncthreads();

    float s = ent[sub][dl];
#pragma unroll
    for (int i = 0; i < CPS; ++i) {
        bst0[base + (size_t)i * DD] = s;
        s = Pr[i] * s + Qr[i];
    }

    // scalar a-scan over 512 chunks: pair-compose -> 256-wide Hillis-Steele
    if (dt == 0) {
        const int cbase = b * NCH;
        const float p0 = PaBuf[cbase + 2 * tid],     q0 = QaBuf[cbase + 2 * tid];
        const float p1 = PaBuf[cbase + 2 * tid + 1], q1 = QaBuf[cbase + 2 * tid + 1];
        float Pc = p1 * p0;
        float Qc = p1 * q0 + q1;
#pragma unroll
        for (int off = 1; off < 256; off <<= 1) {
            sPa[tid] = Pc; sQa[tid] = Qc;
            __syncthreads();
            if (tid >= off) {
                const float pp = sPa[tid - off], qq = sQa[tid - off];
                Qc = Pc * qq + Qc;
                Pc = Pc * pp;
            }
            __syncthreads();
        }
        sQa[tid] = Qc;
        __syncthreads();
        const float E = (tid == 0) ? 0.f : sQa[tid - 1];
        a0[cbase + 2 * tid]     = E;
        a0[cbase + 2 * tid + 1] = p0 * E + q0;
    }
}

// ---------------------------------------------------------------------------
// Pass 3 (pipelined): each wave replays KCH=4 consecutive chunks; side-band
// loads of chunk k+1 fly under replay+LN of chunk k.
// ---------------------------------------------------------------------------
__global__ __launch_bounds__(NTHR, 2) void pass3_kernel(
    const unsigned* __restrict__ DTb,
    const float* __restrict__ lnw, const float* __restrict__ lnb,
    const float* __restrict__ bst0, const float* __restrict__ a0,
    const float2* __restrict__ MEbuf,
    float* __restrict__ out)
{
    const int wv   = threadIdx.x >> 6;
    const int lane = threadIdx.x & 63;
    const int wid  = blockIdx.x * WPB + wv;
    const int gc0  = wid * KCH;
    const int b    = gc0 >> 9;
    const int ch0  = gc0 & (NCH - 1);
    const int d2   = lane << 1;

    const size_t base = ((size_t)b * SS + ch0 * TT) * DD + d2;
    const uint2* DTp = (const uint2*)(DTb + base);
    float2* Op = (float2*)(out + base);

    const float2 gw = *(const float2*)(lnw + d2);
    const float2 gb = *(const float2*)(lnb + d2);

    uint2 dtA[TT], dtB[TT];
    float2 meA, meB, bstA, bstB;
    float aA, aB;

#define LD3(X, k) do { \
    const int off_ = (k) * (TT * DD / 2); \
    _Pragma("unroll") \
    for (int t = 0; t < TT; ++t) dt##X[t] = DTp[off_ + t * (DD / 2)]; \
    me##X  = MEbuf[(size_t)b * SS + (ch0 + (k)) * TT + (lane & (TT - 1))]; \
    bst##X = *(const float2*)(bst0 + (size_t)(gc0 + (k)) * DD + d2); \
    a##X   = a0[gc0 + (k)]; \
} while (0)

#define CH3(X, k) do { \
    float a = a##X; \
    float2 bst = bst##X; \
    float2 o[TT]; float s1p[TT], s2p[TT]; \
    _Pragma("unroll") \
    for (int t = 0; t < TT; ++t) { \
        const float mt = __int_as_float(__builtin_amdgcn_readlane(__float_as_int(me##X.x), t)); \
        const float et = __int_as_float(__builtin_amdgcn_readlane(__float_as_int(me##X.y), t)); \
        a = mt * a + et; \
        bst.x = up_lo(dt##X[t].x) * bst.x + up_hi(dt##X[t].x); \
        bst.y = up_lo(dt##X[t].y) * bst.y + up_hi(dt##X[t].y); \
        const float inva = fast_rcp(a + REC_EPS); \
        o[t].x = bst.x * inva; o[t].y = bst.y * inva; \
        s1p[t] = o[t].x + o[t].y; \
        s2p[t] = o[t].x * o[t].x + o[t].y * o[t].y; \
    } \
    _Pragma("unroll") \
    for (int t = 0; t < TT; ++t) wave_red2(s1p[t], s2p[t]); \
    const int off_ = (k) * (TT * DD / 2); \
    _Pragma("unroll") \
    for (int t = 0; t < TT; ++t) { \
        const float mu  = s1p[t] * (1.0f / DD); \
        const float var = s2p[t] * (1.0f / DD) - mu * mu; \
        const float rs  = rsqrtf(var + LN_EPS); \
        float2 r; \
        r.x = (o[t].x - mu) * rs * gw.x + gb.x; \
        r.y = (o[t].y - mu) * rs * gw.y + gb.y; \
        Op[off_ + t * (DD / 2)] = r; \
    } \
} while (0)

    LD3(A, 0);
    LD3(B, 1);
    CH3(A, 0);
    LD3(A, 2);
    CH3(B, 1);
    LD3(B, 3);
    CH3(A, 2);
    CH3(B, 3);

#undef LD3
#undef CH3
}

extern "C" void kernel_launch(void* const* d_in, const int* in_sizes, int n_in,
                              void* d_out, int out_size, void* d_ws, size_t ws_size,
                              hipStream_t stream)
{
    const float* C    = (const float*)d_in[0];
    const float* V    = (const float*)d_in[1];
    const float* W    = (const float*)d_in[2];
    const float* enc  = (const float*)d_in[3];
    const float* tmod = (const float*)d_in[4];
    const float* cmod = (const float*)d_in[5];
    const float* lnw  = (const float*)d_in[6];
    const float* lnb  = (const float*)d_in[7];
    float* out = (float*)d_out;

    // Workspace layout: DT side-band (33.5 MB) + scan buffers (~13 MB)
    float* ws    = (float*)d_ws;
    unsigned* DTbuf = (unsigned*)ws;                      // BB*SS*DD uints
    float* Pbuf  = ws    + (size_t)BB * SS * DD;          // BB*NCH*DD
    float* Qbuf  = Pbuf  + (size_t)BB * NCH * DD;
    float* bst0  = Qbuf  + (size_t)BB * NCH * DD;
    float2* MEbuf = (float2*)(bst0 + (size_t)BB * NCH * DD);  // BB*SS float2
    float* PaBuf = (float*)(MEbuf + (size_t)BB * SS);         // BB*NCH
    float* QaBuf = PaBuf + (size_t)BB * NCH;
    float* a0Buf = QaBuf + (size_t)BB * NCH;

    pass1_kernel<<<NBLK1, NTHR, 0, stream>>>(C, V, W, enc, tmod, cmod, DTbuf,
                                             Pbuf, Qbuf, PaBuf, QaBuf, MEbuf);
    pass2_kernel<<<BB * 8, 256, 0, stream>>>(Pbuf, Qbuf, PaBuf, QaBuf, bst0, a0Buf);
    pass3_kernel<<<NBLK1, NTHR, 0, stream>>>(DTbuf, lnw, lnb,
                                             bst0, a0Buf, MEbuf, out);
}